// Round 3
// baseline (807.157 us; speedup 1.0000x reference)
//
#include <hip/hip_runtime.h>
#include <hip/hip_bf16.h>
#include <stdint.h>

#define NTOK 8192
#define NE 8
#define DIN 1024
#define DH 4096
#define DOUT 1024
#define MAXMB2 71  // max m-blocks at BM=256: 16384/256 + 7 partial tails

typedef __bf16 bf16;
typedef __bf16 bf16_8 __attribute__((ext_vector_type(8)));
typedef __bf16 bf16_4 __attribute__((ext_vector_type(4)));
typedef float f32_4 __attribute__((ext_vector_type(4)));

__device__ __forceinline__ void gl_lds16(const void* g, void* l) {
  __builtin_amdgcn_global_load_lds(
      (const __attribute__((address_space(1))) unsigned int*)g,
      (__attribute__((address_space(3))) unsigned int*)l, 16, 0, 0);
}

// bijective XCD swizzle (m204 form): works for any nwg
__device__ __forceinline__ int xcd_swz(int orig, int nwg) {
  int q = nwg >> 3, r = nwg & 7;
  int x = orig & 7, i = orig >> 3;
  return (x < r ? x * (q + 1) : r * (q + 1) + (x - r) * q) + i;
}

// ---------------- gating: fp32 logits, top-2, softmax (NO atomics) ----------
__global__ void gate_kernel(const float* __restrict__ x, const float* __restrict__ Wg,
                            const float* __restrict__ bg,
                            int* __restrict__ topi, float* __restrict__ topw) {
  int t = blockIdx.x * 4 + (threadIdx.x >> 6);
  int lane = threadIdx.x & 63;
  float acc[NE];
#pragma unroll
  for (int e = 0; e < NE; e++) acc[e] = 0.f;
  const float* xr = x + (size_t)t * DIN;
#pragma unroll
  for (int i = 0; i < DIN / 64; i++) {
    float xv = xr[lane + 64 * i];
    const float4* wr = (const float4*)(Wg + (size_t)(lane + 64 * i) * NE);
    float4 w0 = wr[0], w1 = wr[1];
    acc[0] += xv * w0.x; acc[1] += xv * w0.y; acc[2] += xv * w0.z; acc[3] += xv * w0.w;
    acc[4] += xv * w1.x; acc[5] += xv * w1.y; acc[6] += xv * w1.z; acc[7] += xv * w1.w;
  }
#pragma unroll
  for (int off = 32; off > 0; off >>= 1)
#pragma unroll
    for (int e = 0; e < NE; e++) acc[e] += __shfl_xor(acc[e], off, 64);
  if (lane == 0) {
    float lg[NE];
#pragma unroll
    for (int e = 0; e < NE; e++) lg[e] = acc[e] + bg[e];
    int i0 = 0; float v0 = lg[0];
#pragma unroll
    for (int e = 1; e < NE; e++) if (lg[e] > v0) { v0 = lg[e]; i0 = e; }
    int i1 = -1; float v1 = -3.0e38f;
#pragma unroll
    for (int e = 0; e < NE; e++) if (e != i0 && lg[e] > v1) { v1 = lg[e]; i1 = e; }
    float ex = expf(v1 - v0);
    float w0 = 1.f / (1.f + ex);
    float w1 = ex / (1.f + ex);
    topi[2 * t] = i0; topi[2 * t + 1] = i1;
    topw[2 * t] = w0; topw[2 * t + 1] = w1;
  }
}

// ---------------- histogram: block-aggregated positions ---------------------
__global__ void hist_kernel(const int* __restrict__ topi, int* __restrict__ counts,
                            int* __restrict__ pos) {
  __shared__ int bins[NE];
  __shared__ int base[NE];
  int tid = threadIdx.x;
  if (tid < NE) bins[tid] = 0;
  __syncthreads();
  int i = blockIdx.x * 256 + tid;  // < 16384
  int e = topi[i];
  int local = atomicAdd(&bins[e], 1);
  __syncthreads();
  if (tid < NE) base[tid] = atomicAdd(&counts[tid], bins[tid]);
  __syncthreads();
  pos[i] = base[e] + local;
}

// offsets[e]: token-slot prefix; mblk_off[e]: 256-row m-block prefix
__global__ void scan_kernel(const int* counts, int* offsets, int* mblk_off) {
  if (threadIdx.x == 0) {
    int s = 0, b = 0;
    for (int e = 0; e < NE; e++) {
      offsets[e] = s; mblk_off[e] = b;
      s += counts[e]; b += (counts[e] + 255) >> 8;
    }
    mblk_off[NE] = b;
  }
}

__global__ void pack_kernel(const int* __restrict__ topi,
                            const int* __restrict__ pos, const int* __restrict__ offsets,
                            int* __restrict__ tok_list, int* __restrict__ slot_of) {
  int i = blockIdx.x * 256 + threadIdx.x;  // < 16384
  int e = topi[i];
  int slot = offsets[e] + pos[i];
  tok_list[slot] = i >> 1;
  slot_of[i] = slot;
}

// ---------------- x fp32 -> bf16 --------------------------------------------
__global__ void cvtx_kernel(const float* __restrict__ x, bf16* __restrict__ xb) {
  size_t i = ((size_t)blockIdx.x * 256 + threadIdx.x) * 8;
  float4 a = *(const float4*)(x + i);
  float4 b = *(const float4*)(x + i + 4);
  bf16_8 o;
  o[0] = (bf16)a.x; o[1] = (bf16)a.y; o[2] = (bf16)a.z; o[3] = (bf16)a.w;
  o[4] = (bf16)b.x; o[5] = (bf16)b.y; o[6] = (bf16)b.z; o[7] = (bf16)b.w;
  *(bf16_8*)(xb + i) = o;
}

// ---------------- transpose + fp32->bf16: dst[n][k] = src[k][n] -------------
__global__ void tcvt_kernel(const float* __restrict__ src, bf16* __restrict__ dst,
                            int src_ld, long long src_es, int dst_ld, long long dst_es) {
  __shared__ bf16 tile[32][33];
  const float* s = src + blockIdx.z * src_es + (size_t)(blockIdx.x * 32) * src_ld + blockIdx.y * 32;
  bf16* d = dst + blockIdx.z * dst_es + (size_t)(blockIdx.y * 32) * dst_ld + blockIdx.x * 32;
  int tid = threadIdx.x;
  int r = tid >> 3, c4 = (tid & 7) * 4;
  float4 v = *(const float4*)(s + (size_t)r * src_ld + c4);
  tile[r][c4] = (bf16)v.x; tile[r][c4 + 1] = (bf16)v.y;
  tile[r][c4 + 2] = (bf16)v.z; tile[r][c4 + 3] = (bf16)v.w;
  __syncthreads();
  int n = tid >> 3, k4 = (tid & 7) * 4;
  bf16_4 o;
  o[0] = tile[k4][n]; o[1] = tile[k4 + 1][n]; o[2] = tile[k4 + 2][n]; o[3] = tile[k4 + 3][n];
  *(bf16_4*)(d + (size_t)n * dst_ld + k4) = o;
}

// ============================================================================
// 256x256 8-wave GEMM, BK=64, dbuf 128KB LDS, 4 phases/K-tile (HK template).
// LDS layout per buf: A[256][64] bf16 (32KB) with 16B-chunk swizzle
//   phys[row][s] = logical[row][s ^ (row&7)]  -> conflict-free ds_read_b128,
//   staged with LINEAR gl_lds dest + inverse-swizzled global source (rule #21).
// Staging: thread t covers rows {t>>3 +0,64,128,192} at col-chunk (t&7)^((t>>3)&7).
// Pipeline: stage(kt+1) issued in phases 0-1 of kt; vmcnt(0)+barrier at iter top
// (issue-to-wait distance >= 2 phases ~ >700cy, covers L2-class latency).
// ============================================================================

#define MFMA_ARGS 0, 0, 0

__global__ __launch_bounds__(512, 2) void gemm1_kernel(
    const bf16* __restrict__ xb, const bf16* __restrict__ W1t,
    const float* __restrict__ b1, const int* __restrict__ counts,
    const int* __restrict__ offsets, const int* __restrict__ mblk_off,
    const int* __restrict__ tok_list,
    bf16* __restrict__ h, int hchunk, int hc0) {
  extern __shared__ __align__(16) bf16 smem[];
  int gx = gridDim.x;
  int nwg = gx * gridDim.y;
  int orig = blockIdx.y * gx + blockIdx.x;
  int wgid = xcd_swz(orig, nwg);
  int bx = wgid % gx;
  int mb = wgid / gx;
  if (mb >= mblk_off[NE]) return;
  int e = 0;
  while (mb >= mblk_off[e + 1]) e++;
  int ne = counts[e];
  int m0 = (mb - mblk_off[e]) * 256;
  int off = offsets[e];
  int n0 = bx * 256;

  int t = threadIdx.x;
  int w = t >> 6, lane = t & 63;
  int wm = w >> 2, wn = w & 3;
  int lr = lane & 15, qd = lane >> 4;
  int cx0 = (qd ^ (lr & 7)) << 3;        // elem offset of k-chunk, kk=0
  int cx1 = ((4 + qd) ^ (lr & 7)) << 3;  // kk=1

  // staging: 4 rows/thread, one col-chunk
  int r0 = t >> 3;
  int cA = ((t & 7) ^ (r0 & 7)) << 3;  // source col (elems) within K-tile
  const bf16* gA[4]; const bf16* gB[4];
#pragma unroll
  for (int j = 0; j < 4; j++) {
    int r = r0 + j * 64;
    int slot = off + m0 + r;
    int mx = off + ne - 1;
    if (slot > mx) slot = mx;  // clamp tail rows (ne>=1 whenever block exists)
    gA[j] = xb + (size_t)tok_list[slot] * DIN + cA;
    gB[j] = W1t + ((size_t)e * hchunk + n0 + r) * DIN + cA;
  }

  auto stageA = [&](int nb) {
    bf16* db = smem + nb * 16384 + w * 512;
    gl_lds16(gA[0], db); gl_lds16(gA[1], db + 4096);
    gl_lds16(gA[2], db + 8192); gl_lds16(gA[3], db + 12288);
  };
  auto stageB = [&](int nb) {
    bf16* db = smem + 32768 + nb * 16384 + w * 512;
    gl_lds16(gB[0], db); gl_lds16(gB[1], db + 4096);
    gl_lds16(gB[2], db + 8192); gl_lds16(gB[3], db + 12288);
  };

  f32_4 acc[8][4];
#pragma unroll
  for (int i = 0; i < 8; i++)
#pragma unroll
    for (int j = 0; j < 4; j++) acc[i][j] = (f32_4){0.f, 0.f, 0.f, 0.f};

  const int nk = DIN / 64;  // 16
  stageA(0); stageB(0);
#pragma unroll
  for (int j = 0; j < 4; j++) { gA[j] += 64; gB[j] += 64; }

#pragma unroll 1
  for (int kt = 0; kt < nk; kt++) {
    asm volatile("s_waitcnt vmcnt(0)" ::: "memory");
    __builtin_amdgcn_s_barrier();
    __builtin_amdgcn_sched_barrier(0);
    int cb = kt & 1, nb = cb ^ 1;
    const bf16* pa = smem + cb * 16384 + (wm * 128 + lr) * 64;
    const bf16* pb = smem + 32768 + cb * 16384 + (wn * 64 + lr) * 64;
    bool pf = (kt + 1 < nk);
    bf16_8 a_[4], fb0[4], fb1[4];
    // ---- phase 0: stage A(kt+1) | read b(kk0)+a(mh0,kk0) | mfma
    if (pf) stageA(nb);
    __builtin_amdgcn_sched_barrier(0);
#pragma unroll
    for (int i = 0; i < 4; i++) {
      fb0[i] = *(const bf16_8*)(pb + i * 1024 + cx0);
      a_[i] = *(const bf16_8*)(pa + i * 1024 + cx0);
    }
    __builtin_amdgcn_sched_barrier(0);
    __builtin_amdgcn_s_barrier();
    asm volatile("s_waitcnt lgkmcnt(0)" ::: "memory");
    __builtin_amdgcn_sched_barrier(0);
    __builtin_amdgcn_s_setprio(1);
#pragma unroll
    for (int m2 = 0; m2 < 4; m2++)
#pragma unroll
      for (int n2 = 0; n2 < 4; n2++)
        acc[m2][n2] = __builtin_amdgcn_mfma_f32_16x16x32_bf16(a_[m2], fb0[n2], acc[m2][n2], MFMA_ARGS);
    __builtin_amdgcn_s_setprio(0);
    __builtin_amdgcn_sched_barrier(0);
    __builtin_amdgcn_s_barrier();
    // ---- phase 1: stage B(kt+1) | read a(mh1,kk0) | mfma
    if (pf) stageB(nb);
    __builtin_amdgcn_sched_barrier(0);
#pragma unroll
    for (int i = 0; i < 4; i++) a_[i] = *(const bf16_8*)(pa + (4 + i) * 1024 + cx0);
    __builtin_amdgcn_sched_barrier(0);
    __builtin_amdgcn_s_barrier();
    asm volatile("s_waitcnt lgkmcnt(0)" ::: "memory");
    __builtin_amdgcn_sched_barrier(0);
    __builtin_amdgcn_s_setprio(1);
#pragma unroll
    for (int m2 = 0; m2 < 4; m2++)
#pragma unroll
      for (int n2 = 0; n2 < 4; n2++)
        acc[4 + m2][n2] = __builtin_amdgcn_mfma_f32_16x16x32_bf16(a_[m2], fb0[n2], acc[4 + m2][n2], MFMA_ARGS);
    __builtin_amdgcn_s_setprio(0);
    __builtin_amdgcn_sched_barrier(0);
    __builtin_amdgcn_s_barrier();
    // ---- phase 2: read b(kk1)+a(mh0,kk1) | mfma
#pragma unroll
    for (int i = 0; i < 4; i++) {
      fb1[i] = *(const bf16_8*)(pb + i * 1024 + cx1);
      a_[i] = *(const bf16_8*)(pa + i * 1024 + cx1);
    }
    __builtin_amdgcn_sched_barrier(0);
    __builtin_amdgcn_s_barrier();
    asm volatile("s_waitcnt lgkmcnt(0)" ::: "memory");
    __builtin_amdgcn_sched_barrier(0);
    __builtin_amdgcn_s_setprio(1);
#pragma unroll
    for (int m2 = 0; m2 < 4; m2++)
#pragma unroll
      for (int n2 = 0; n2 < 4; n2++)
        acc[m2][n2] = __builtin_amdgcn_mfma_f32_16x16x32_bf16(a_[m2], fb1[n2], acc[m2][n2], MFMA_ARGS);
    __builtin_amdgcn_s_setprio(0);
    __builtin_amdgcn_sched_barrier(0);
    __builtin_amdgcn_s_barrier();
    // ---- phase 3: read a(mh1,kk1) | mfma
#pragma unroll
    for (int i = 0; i < 4; i++) a_[i] = *(const bf16_8*)(pa + (4 + i) * 1024 + cx1);
    __builtin_amdgcn_sched_barrier(0);
    __builtin_amdgcn_s_barrier();
    asm volatile("s_waitcnt lgkmcnt(0)" ::: "memory");
    __builtin_amdgcn_sched_barrier(0);
    __builtin_amdgcn_s_setprio(1);
#pragma unroll
    for (int m2 = 0; m2 < 4; m2++)
#pragma unroll
      for (int n2 = 0; n2 < 4; n2++)
        acc[4 + m2][n2] = __builtin_amdgcn_mfma_f32_16x16x32_bf16(a_[m2], fb1[n2], acc[4 + m2][n2], MFMA_ARGS);
    __builtin_amdgcn_s_setprio(0);
    __builtin_amdgcn_sched_barrier(0);
    __builtin_amdgcn_s_barrier();
    if (pf) {
#pragma unroll
      for (int j = 0; j < 4; j++) { gA[j] += 64; gB[j] += 64; }
    }
  }

  // ---- epilogue: bias+relu, bounce 256x256 bf16 C tile through LDS ---------
  // row-major [256][512B], 32B-slot XOR: byte ^= ((row>>2)&3)<<5 (conflict-free)
#pragma unroll
  for (int nt = 0; nt < 4; nt++) {
    int col = wn * 64 + nt * 16 + lr;
    float bias = b1[(size_t)e * DH + hc0 + n0 + col];
#pragma unroll
    for (int mt = 0; mt < 8; mt++) {
#pragma unroll
      for (int r2 = 0; r2 < 4; r2++) {
        int row = wm * 128 + mt * 16 + qd * 4 + r2;
        float v = acc[mt][nt][r2] + bias;
        v = v > 0.f ? v : 0.f;
        int byte = ((row << 9) + (col << 1)) ^ (((row >> 2) & 3) << 5);
        *(bf16*)((char*)smem + byte) = (bf16)v;
      }
    }
  }
  __syncthreads();
#pragma unroll
  for (int p = 0; p < 16; p++) {
    int row = p * 16 + (t >> 5);
    int cc = t & 31;
    if (m0 + row < ne) {
      int byte = (((row << 9) + (cc << 4))) ^ (((row >> 2) & 3) << 5);
      bf16_8 v = *(const bf16_8*)((char*)smem + byte);
      *(bf16_8*)(h + (size_t)(off + m0 + row) * hchunk + n0 + cc * 8) = v;
    }
  }
}

// ---------------- GEMM2: y[slot] += h @ W2t^T  (K-split x2, fp32 atomics) ---
__global__ __launch_bounds__(512, 2) void gemm2_kernel(
    const bf16* __restrict__ h, const bf16* __restrict__ W2t,
    const int* __restrict__ counts, const int* __restrict__ offsets,
    const int* __restrict__ mblk_off,
    float* __restrict__ y, int hchunk) {
  extern __shared__ __align__(16) bf16 smem[];
  int gx = gridDim.x, gy = gridDim.y;
  int nwg = gx * gy * gridDim.z;
  int orig = (blockIdx.z * gy + blockIdx.y) * gx + blockIdx.x;
  int wgid = xcd_swz(orig, nwg);
  int bx = wgid % gx;
  int rest = wgid / gx;
  int mb = rest % gy;
  int z = rest / gy;
  if (mb >= mblk_off[NE]) return;
  int e = 0;
  while (mb >= mblk_off[e + 1]) e++;
  int ne = counts[e];
  int m0 = (mb - mblk_off[e]) * 256;
  int off = offsets[e];
  int n0 = bx * 256;
  int k0 = z * (hchunk >> 1);

  int t = threadIdx.x;
  int w = t >> 6, lane = t & 63;
  int wm = w >> 2, wn = w & 3;
  int lr = lane & 15, qd = lane >> 4;
  int cx0 = (qd ^ (lr & 7)) << 3;
  int cx1 = ((4 + qd) ^ (lr & 7)) << 3;

  int r0 = t >> 3;
  int cA = ((t & 7) ^ (r0 & 7)) << 3;
  const bf16* gA[4]; const bf16* gB[4];
#pragma unroll
  for (int j = 0; j < 4; j++) {
    int r = r0 + j * 64;
    gA[j] = h + (size_t)(off + m0 + r) * hchunk + k0 + cA;  // h padded +256 rows
    gB[j] = W2t + ((size_t)e * DOUT + n0 + r) * hchunk + k0 + cA;
  }

  auto stageA = [&](int nb) {
    bf16* db = smem + nb * 16384 + w * 512;
    gl_lds16(gA[0], db); gl_lds16(gA[1], db + 4096);
    gl_lds16(gA[2], db + 8192); gl_lds16(gA[3], db + 12288);
  };
  auto stageB = [&](int nb) {
    bf16* db = smem + 32768 + nb * 16384 + w * 512;
    gl_lds16(gB[0], db); gl_lds16(gB[1], db + 4096);
    gl_lds16(gB[2], db + 8192); gl_lds16(gB[3], db + 12288);
  };

  f32_4 acc[8][4];
#pragma unroll
  for (int i = 0; i < 8; i++)
#pragma unroll
    for (int j = 0; j < 4; j++) acc[i][j] = (f32_4){0.f, 0.f, 0.f, 0.f};

  const int nk = hchunk >> 7;  // K-tiles per z-half
  stageA(0); stageB(0);
#pragma unroll
  for (int j = 0; j < 4; j++) { gA[j] += 64; gB[j] += 64; }

#pragma unroll 1
  for (int kt = 0; kt < nk; kt++) {
    asm volatile("s_waitcnt vmcnt(0)" ::: "memory");
    __builtin_amdgcn_s_barrier();
    __builtin_amdgcn_sched_barrier(0);
    int cb = kt & 1, nb = cb ^ 1;
    const bf16* pa = smem + cb * 16384 + (wm * 128 + lr) * 64;
    const bf16* pb = smem + 32768 + cb * 16384 + (wn * 64 + lr) * 64;
    bool pf = (kt + 1 < nk);
    bf16_8 a_[4], fb0[4], fb1[4];
    // ---- phase 0
    if (pf) stageA(nb);
    __builtin_amdgcn_sched_barrier(0);
#pragma unroll
    for (int i = 0; i < 4; i++) {
      fb0[i] = *(const bf16_8*)(pb + i * 1024 + cx0);
      a_[i] = *(const bf16_8*)(pa + i * 1024 + cx0);
    }
    __builtin_amdgcn_sched_barrier(0);
    __builtin_amdgcn_s_barrier();
    asm volatile("s_waitcnt lgkmcnt(0)" ::: "memory");
    __builtin_amdgcn_sched_barrier(0);
    __builtin_amdgcn_s_setprio(1);
#pragma unroll
    for (int m2 = 0; m2 < 4; m2++)
#pragma unroll
      for (int n2 = 0; n2 < 4; n2++)
        acc[m2][n2] = __builtin_amdgcn_mfma_f32_16x16x32_bf16(a_[m2], fb0[n2], acc[m2][n2], MFMA_ARGS);
    __builtin_amdgcn_s_setprio(0);
    __builtin_amdgcn_sched_barrier(0);
    __builtin_amdgcn_s_barrier();
    // ---- phase 1
    if (pf) stageB(nb);
    __builtin_amdgcn_sched_barrier(0);
#pragma unroll
    for (int i = 0; i < 4; i++) a_[i] = *(const bf16_8*)(pa + (4 + i) * 1024 + cx0);
    __builtin_amdgcn_sched_barrier(0);
    __builtin_amdgcn_s_barrier();
    asm volatile("s_waitcnt lgkmcnt(0)" ::: "memory");
    __builtin_amdgcn_sched_barrier(0);
    __builtin_amdgcn_s_setprio(1);
#pragma unroll
    for (int m2 = 0; m2 < 4; m2++)
#pragma unroll
      for (int n2 = 0; n2 < 4; n2++)
        acc[4 + m2][n2] = __builtin_amdgcn_mfma_f32_16x16x32_bf16(a_[m2], fb0[n2], acc[4 + m2][n2], MFMA_ARGS);
    __builtin_amdgcn_s_setprio(0);
    __builtin_amdgcn_sched_barrier(0);
    __builtin_amdgcn_s_barrier();
    // ---- phase 2
#pragma unroll
    for (int i = 0; i < 4; i++) {
      fb1[i] = *(const bf16_8*)(pb + i * 1024 + cx1);
      a_[i] = *(const bf16_8*)(pa + i * 1024 + cx1);
    }
    __builtin_amdgcn_sched_barrier(0);
    __builtin_amdgcn_s_barrier();
    asm volatile("s_waitcnt lgkmcnt(0)" ::: "memory");
    __builtin_amdgcn_sched_barrier(0);
    __builtin_amdgcn_s_setprio(1);
#pragma unroll
    for (int m2 = 0; m2 < 4; m2++)
#pragma unroll
      for (int n2 = 0; n2 < 4; n2++)
        acc[m2][n2] = __builtin_amdgcn_mfma_f32_16x16x32_bf16(a_[m2], fb1[n2], acc[m2][n2], MFMA_ARGS);
    __builtin_amdgcn_s_setprio(0);
    __builtin_amdgcn_sched_barrier(0);
    __builtin_amdgcn_s_barrier();
    // ---- phase 3
#pragma unroll
    for (int i = 0; i < 4; i++) a_[i] = *(const bf16_8*)(pa + (4 + i) * 1024 + cx1);
    __builtin_amdgcn_sched_barrier(0);
    __builtin_amdgcn_s_barrier();
    asm volatile("s_waitcnt lgkmcnt(0)" ::: "memory");
    __builtin_amdgcn_sched_barrier(0);
    __builtin_amdgcn_s_setprio(1);
#pragma unroll
    for (int m2 = 0; m2 < 4; m2++)
#pragma unroll
      for (int n2 = 0; n2 < 4; n2++)
        acc[4 + m2][n2] = __builtin_amdgcn_mfma_f32_16x16x32_bf16(a_[m2], fb1[n2], acc[4 + m2][n2], MFMA_ARGS);
    __builtin_amdgcn_s_setprio(0);
    __builtin_amdgcn_sched_barrier(0);
    __builtin_amdgcn_s_barrier();
    if (pf) {
#pragma unroll
      for (int j = 0; j < 4; j++) { gA[j] += 64; gB[j] += 64; }
    }
  }

  // ---- epilogue: fp32 atomic accumulate into zeroed y ----------------------
#pragma unroll
  for (int mt = 0; mt < 8; mt++) {
#pragma unroll
    for (int r2 = 0; r2 < 4; r2++) {
      int row = wm * 128 + mt * 16 + qd * 4 + r2;
      if (m0 + row < ne) {
        float* yr = y + (size_t)(off + m0 + row) * DOUT + n0;
#pragma unroll
        for (int nt = 0; nt < 4; nt++)
          atomicAdd(yr + wn * 64 + nt * 16 + lr, acc[mt][nt][r2]);
      }
    }
  }
}

// ---------------- combine: out[t] = sum_k w_k * (y[slot_k] + b2[e_k]) -------
__global__ void combine_kernel(const int* __restrict__ topi, const float* __restrict__ topw,
                               const int* __restrict__ slot_of, const float* __restrict__ y,
                               const float* __restrict__ b2, float* __restrict__ out) {
  int t = blockIdx.x;
  int c = threadIdx.x * 4;
  int e0 = topi[2 * t], e1 = topi[2 * t + 1];
  float w0 = topw[2 * t], w1 = topw[2 * t + 1];
  int s0 = slot_of[2 * t], s1 = slot_of[2 * t + 1];
  float4 a = *(const float4*)(y + (size_t)s0 * DOUT + c);
  float4 b = *(const float4*)(y + (size_t)s1 * DOUT + c);
  float4 p = *(const float4*)(b2 + (size_t)e0 * DOUT + c);
  float4 q = *(const float4*)(b2 + (size_t)e1 * DOUT + c);
  float4 o;
  o.x = w0 * (a.x + p.x) + w1 * (b.x + q.x);
  o.y = w0 * (a.y + p.y) + w1 * (b.y + q.y);
  o.z = w0 * (a.z + p.z) + w1 * (b.z + q.z);
  o.w = w0 * (a.w + p.w) + w1 * (b.w + q.w);
  *(float4*)(out + (size_t)t * DOUT + c) = o;
}

// ---------------- host ------------------------------------------------------
extern "C" void kernel_launch(void* const* d_in, const int* in_sizes, int n_in,
                              void* d_out, int out_size, void* d_ws, size_t ws_size,
                              hipStream_t stream) {
  const float* x  = (const float*)d_in[0];
  const float* Wg = (const float*)d_in[1];
  const float* bg = (const float*)d_in[2];
  const float* W1 = (const float*)d_in[3];
  const float* b1 = (const float*)d_in[4];
  const float* W2 = (const float*)d_in[5];
  const float* b2 = (const float*)d_in[6];
  float* out = (float*)d_out;

  static bool attrset = false;
  if (!attrset) {
    hipFuncSetAttribute((const void*)gemm1_kernel,
                        hipFuncAttributeMaxDynamicSharedMemorySize, 131072);
    hipFuncSetAttribute((const void*)gemm2_kernel,
                        hipFuncAttributeMaxDynamicSharedMemorySize, 131072);
    attrset = true;
  }

  char* p = (char*)d_ws;
  int*   counts   = (int*)p;   p += 256;
  int*   offsets  = (int*)p;   p += 256;
  int*   mblk_off = (int*)p;   p += 256;
  int*   topi     = (int*)p;   p += 16384 * 4;
  float* topw     = (float*)p; p += 16384 * 4;
  int*   pos      = (int*)p;   p += 16384 * 4;
  int*   tok_list = (int*)p;   p += 16384 * 4;
  int*   slot_of  = (int*)p;   p += 16384 * 4;
  bf16*  xb       = (bf16*)p;  p += (size_t)NTOK * DIN * 2;
  float* y        = (float*)p; p += (size_t)16384 * DOUT * 4;  // 67 MB

  size_t fixedBytes = (size_t)(p - (char*)d_ws);
  // per-hchunk bytes: h (16384+256)*2 + W1t 8*1024*2 + W2t 8*1024*2 = 66048
  int hchunk = 4096;
  while (hchunk > 256 && fixedBytes + (size_t)hchunk * 66048 > ws_size) hchunk >>= 1;

  bf16* W1t  = (bf16*)p; p += (size_t)NE * hchunk * DIN * 2;
  bf16* W2t  = (bf16*)p; p += (size_t)NE * DOUT * hchunk * 2;
  bf16* hbuf = (bf16*)p; p += (size_t)(16384 + 256) * hchunk * 2;

  hipMemsetAsync(counts, 0, 32, stream);
  hipMemsetAsync(y, 0, (size_t)16384 * DOUT * 4, stream);
  gate_kernel<<<NTOK / 4, 256, 0, stream>>>(x, Wg, bg, topi, topw);
  cvtx_kernel<<<(NTOK * DIN) / (8 * 256), 256, 0, stream>>>(x, xb);
  hist_kernel<<<64, 256, 0, stream>>>(topi, counts, pos);
  scan_kernel<<<1, 64, 0, stream>>>(counts, offsets, mblk_off);
  pack_kernel<<<64, 256, 0, stream>>>(topi, pos, offsets, tok_list, slot_of);

  int nchunks = DH / hchunk;
  for (int c = 0; c < nchunks; c++) {
    int hc0 = c * hchunk;
    // W1t[e][n][k] = W1[e][k][hc0+n]  (k rows: 1024, n cols: hchunk)
    tcvt_kernel<<<dim3(DIN / 32, hchunk / 32, NE), 256, 0, stream>>>(
        W1 + hc0, W1t, DH, (long long)DIN * DH, DIN, (long long)hchunk * DIN);
    // W2t[e][o][hk] = W2[e][hc0+hk][o] (hk rows: hchunk, o cols: 1024)
    tcvt_kernel<<<dim3(hchunk / 32, DOUT / 32, NE), 256, 0, stream>>>(
        W2 + (size_t)hc0 * DOUT, W2t, DOUT, (long long)DH * DOUT, hchunk, (long long)DOUT * hchunk);
    gemm1_kernel<<<dim3(hchunk / 256, MAXMB2), 512, 131072, stream>>>(
        xb, W1t, b1, counts, offsets, mblk_off, tok_list, hbuf, hchunk, hc0);
    gemm2_kernel<<<dim3(DOUT / 256, MAXMB2, 2), 512, 131072, stream>>>(
        hbuf, W2t, counts, offsets, mblk_off, y, hchunk);
  }
  combine_kernel<<<NTOK, 256, 0, stream>>>(topi, topw, slot_of, y, b2, out);
}

// Round 5
// 776.377 us; speedup vs baseline: 1.0396x; 1.0396x over previous
//
#include <hip/hip_runtime.h>
#include <hip/hip_bf16.h>
#include <stdint.h>

#define NTOK 8192
#define NE 8
#define DIN 1024
#define DH 4096
#define DOUT 1024
#define MAXMB 135  // max total m-blocks: 16384/128 + 7 partial tails

typedef __bf16 bf16;
typedef __bf16 bf16_8 __attribute__((ext_vector_type(8)));
typedef __bf16 bf16_4 __attribute__((ext_vector_type(4)));
typedef float f32_4 __attribute__((ext_vector_type(4)));

__device__ __forceinline__ void gl_lds16(const void* g, void* l) {
  __builtin_amdgcn_global_load_lds(
      (const __attribute__((address_space(1))) unsigned int*)g,
      (__attribute__((address_space(3))) unsigned int*)l, 16, 0, 0);
}

// ---------------- gating: fp32 logits, top-2, softmax; fused x->bf16 --------
__global__ void gate_kernel(const float* __restrict__ x, const float* __restrict__ Wg,
                            const float* __restrict__ bg,
                            int* __restrict__ topi, float* __restrict__ topw,
                            bf16* __restrict__ xb) {
  int t = blockIdx.x * 4 + (threadIdx.x >> 6);
  int lane = threadIdx.x & 63;
  float acc[NE];
#pragma unroll
  for (int e = 0; e < NE; e++) acc[e] = 0.f;
  const float* xr = x + (size_t)t * DIN;
  bf16* xw = xb + (size_t)t * DIN;
#pragma unroll
  for (int i = 0; i < DIN / 64; i++) {
    float xv = xr[lane + 64 * i];
    xw[lane + 64 * i] = (bf16)xv;  // fused fp32->bf16 conversion (was cvtx)
    const float4* wr = (const float4*)(Wg + (size_t)(lane + 64 * i) * NE);
    float4 w0 = wr[0], w1 = wr[1];
    acc[0] += xv * w0.x; acc[1] += xv * w0.y; acc[2] += xv * w0.z; acc[3] += xv * w0.w;
    acc[4] += xv * w1.x; acc[5] += xv * w1.y; acc[6] += xv * w1.z; acc[7] += xv * w1.w;
  }
#pragma unroll
  for (int off = 32; off > 0; off >>= 1)
#pragma unroll
    for (int e = 0; e < NE; e++) acc[e] += __shfl_xor(acc[e], off, 64);
  if (lane == 0) {
    float lg[NE];
#pragma unroll
    for (int e = 0; e < NE; e++) lg[e] = acc[e] + bg[e];
    int i0 = 0; float v0 = lg[0];
#pragma unroll
    for (int e = 1; e < NE; e++) if (lg[e] > v0) { v0 = lg[e]; i0 = e; }
    int i1 = -1; float v1 = -3.0e38f;
#pragma unroll
    for (int e = 0; e < NE; e++) if (e != i0 && lg[e] > v1) { v1 = lg[e]; i1 = e; }
    float ex = expf(v1 - v0);
    float w0 = 1.f / (1.f + ex);
    float w1 = ex / (1.f + ex);
    topi[2 * t] = i0; topi[2 * t + 1] = i1;
    topw[2 * t] = w0; topw[2 * t + 1] = w1;
  }
}

// ---------------- histogram: block-aggregated positions ---------------------
__global__ void hist_kernel(const int* __restrict__ topi, int* __restrict__ counts,
                            int* __restrict__ pos) {
  __shared__ int bins[NE];
  __shared__ int base[NE];
  int tid = threadIdx.x;
  if (tid < NE) bins[tid] = 0;
  __syncthreads();
  int i = blockIdx.x * 256 + tid;  // < 16384
  int e = topi[i];
  int local = atomicAdd(&bins[e], 1);
  __syncthreads();
  if (tid < NE) base[tid] = atomicAdd(&counts[tid], bins[tid]);
  __syncthreads();
  pos[i] = base[e] + local;
}

// offsets[e]: token-slot prefix; mblk_off[e]: m-block prefix (for grid compaction)
__global__ void scan_kernel(const int* counts, int* offsets, int* mblk_off) {
  if (threadIdx.x == 0) {
    int s = 0, b = 0;
    for (int e = 0; e < NE; e++) {
      offsets[e] = s; mblk_off[e] = b;
      s += counts[e]; b += (counts[e] + 127) >> 7;
    }
    mblk_off[NE] = b;
  }
}

__global__ void pack_kernel(const int* __restrict__ topi,
                            const int* __restrict__ pos, const int* __restrict__ offsets,
                            const float* __restrict__ topw,
                            int* __restrict__ tok_list, float* __restrict__ wt_list) {
  int i = blockIdx.x * 256 + threadIdx.x;  // < 16384
  int e = topi[i];
  int slot = offsets[e] + pos[i];
  tok_list[slot] = i >> 1;
  wt_list[slot] = topw[i];
}

// ---------------- prefill: out[t] = w0*b2[e0] + w1*b2[e1] -------------------
__global__ void prefill_kernel(const int* __restrict__ topi, const float* __restrict__ topw,
                               const float* __restrict__ b2, float* __restrict__ out) {
  int t = blockIdx.x;
  int c = threadIdx.x * 4;
  int e0 = topi[2 * t], e1 = topi[2 * t + 1];
  float w0 = topw[2 * t], w1 = topw[2 * t + 1];
  float4 p = *(const float4*)(b2 + (size_t)e0 * DOUT + c);
  float4 q = *(const float4*)(b2 + (size_t)e1 * DOUT + c);
  float4 o;
  o.x = w0 * p.x + w1 * q.x;
  o.y = w0 * p.y + w1 * q.y;
  o.z = w0 * p.z + w1 * q.z;
  o.w = w0 * p.w + w1 * q.w;
  *(float4*)(out + (size_t)t * DOUT + c) = o;
}

// ---------------- transpose + fp32->bf16: dst[n][k] = src[k][n] -------------
__global__ void tcvt_kernel(const float* __restrict__ src, bf16* __restrict__ dst,
                            int src_ld, long long src_es, int dst_ld, long long dst_es) {
  __shared__ bf16 tile[32][33];
  const float* s = src + blockIdx.z * src_es + (size_t)(blockIdx.x * 32) * src_ld + blockIdx.y * 32;
  bf16* d = dst + blockIdx.z * dst_es + (size_t)(blockIdx.y * 32) * dst_ld + blockIdx.x * 32;
  int tid = threadIdx.x;
  int r = tid >> 3, c4 = (tid & 7) * 4;
  float4 v = *(const float4*)(s + (size_t)r * src_ld + c4);
  tile[r][c4] = (bf16)v.x; tile[r][c4 + 1] = (bf16)v.y;
  tile[r][c4 + 2] = (bf16)v.z; tile[r][c4 + 3] = (bf16)v.w;
  __syncthreads();
  int n = tid >> 3, k4 = (tid & 7) * 4;
  bf16_4 o;
  o[0] = tile[k4][n]; o[1] = tile[k4 + 1][n]; o[2] = tile[k4 + 2][n]; o[3] = tile[k4 + 3][n];
  *(bf16_4*)(d + (size_t)n * dst_ld + k4) = o;
}

// Bank-conflict swizzle: within each 64B LDS row (4 x 16B cols), col' = col ^ ((row&15)>>1) & 3.
// Gather side: lane l in a segment stages global col ((l&3)^(l>>3))&3 of row l>>2,
// keeping lane->LDS contiguity for global_load_lds.

// Pipeline (verified r2, 769us): 3 LDS buffers; per iter: counted vmcnt(4) wait,
// barrier, ISSUE stage of tile kt+2, then ds_read+MFMA of tile kt.

// ---------------- GEMM1: h = relu(gather(xb) @ W1t^T + b1) ------------------
__global__ __launch_bounds__(256) void gemm1_kernel(
    const bf16* __restrict__ xb, const bf16* __restrict__ W1t,
    const float* __restrict__ b1, const int* __restrict__ counts,
    const int* __restrict__ offsets, const int* __restrict__ mblk_off,
    const int* __restrict__ tok_list,
    bf16* __restrict__ h, int hchunk, int hc0) {
  int nbx = gridDim.x;
  int orig = blockIdx.y * nbx + blockIdx.x;
  int nwg = nbx * gridDim.y;
  int wgid = (orig & 7) * (nwg >> 3) + (orig >> 3);
  int bxi = wgid % nbx;
  int mb = wgid / nbx;
  if (mb >= mblk_off[NE]) return;
  int e = 0;
  while (mb >= mblk_off[e + 1]) e++;
  int ne = counts[e];
  int m0 = (mb - mblk_off[e]) * 128;
  int off = offsets[e];
  int n0 = bxi * 128;

  __shared__ __align__(16) bf16 smem[6 * 128 * 32];  // 48 KB: 3 bufs x (A+B)
  bf16* ldsA = smem;
  bf16* ldsB = smem + 3 * 4096;

  int tid = threadIdx.x;
  int w = tid >> 6, lane = tid & 63;
  int scol = (((lane & 3) ^ (lane >> 3)) & 3) * 8;  // swizzled 16B col for staging

  const bf16* gA[2]; const bf16* gB[2];
  bf16* lA[2]; bf16* lB[2];
#pragma unroll
  for (int j = 0; j < 2; j++) {
    int seg = w * 2 + j;
    int row = seg * 16 + (lane >> 2);
    int slot = off + m0 + row;
    int smax = off + ne - 1;
    if (slot > smax) slot = smax;           // clamp tail rows to a valid token
    int tok = tok_list[slot];
    gA[j] = xb + (size_t)tok * DIN + scol;
    lA[j] = ldsA + seg * 512;               // wave-uniform base; HW adds lane*16B
    gB[j] = W1t + ((size_t)e * hchunk + n0 + row) * DIN + scol;
    lB[j] = ldsB + seg * 512;
  }

  f32_4 acc[4][4];
#pragma unroll
  for (int i = 0; i < 4; i++)
#pragma unroll
    for (int j = 0; j < 4; j++) acc[i][j] = (f32_4){0.f, 0.f, 0.f, 0.f};

  int wm = w & 1, wn = w >> 1;
  int lr = lane & 15, quad = lane >> 4;
  int rcol = ((quad ^ (lr >> 1)) & 3) * 8;

  auto compute = [&](int buf) {
    bf16_8 af[4], bfr[4];
#pragma unroll
    for (int mt = 0; mt < 4; mt++)
      af[mt] = *(const bf16_8*)(ldsA + buf * 4096 + (wm * 64 + mt * 16 + lr) * 32 + rcol);
#pragma unroll
    for (int nt = 0; nt < 4; nt++)
      bfr[nt] = *(const bf16_8*)(ldsB + buf * 4096 + (wn * 64 + nt * 16 + lr) * 32 + rcol);
#pragma unroll
    for (int mt = 0; mt < 4; mt++)
#pragma unroll
      for (int nt = 0; nt < 4; nt++)
        acc[mt][nt] = __builtin_amdgcn_mfma_f32_16x16x32_bf16(af[mt], bfr[nt], acc[mt][nt], 0, 0, 0);
  };

  const int nk = DIN / 32;
  // prologue: stage tiles 0,1 into bufs 0,1
#pragma unroll
  for (int j = 0; j < 2; j++) { gl_lds16(gA[j], lA[j]); gl_lds16(gB[j], lB[j]); }
  gA[0] += 32; gA[1] += 32; gB[0] += 32; gB[1] += 32;
#pragma unroll
  for (int j = 0; j < 2; j++) { gl_lds16(gA[j], lA[j] + 4096); gl_lds16(gB[j], lB[j] + 4096); }
  gA[0] += 32; gA[1] += 32; gB[0] += 32; gB[1] += 32;

  int rb = 0, sb = 2;
  for (int kt = 0; kt < nk; kt++) {
    if (kt + 1 < nk) asm volatile("s_waitcnt vmcnt(4)" ::: "memory");
    else             asm volatile("s_waitcnt vmcnt(0)" ::: "memory");
    __builtin_amdgcn_s_barrier();
    __builtin_amdgcn_sched_barrier(0);
    if (kt + 2 < nk) {
#pragma unroll
      for (int j = 0; j < 2; j++) {
        gl_lds16(gA[j], lA[j] + sb * 4096);
        gl_lds16(gB[j], lB[j] + sb * 4096);
      }
      gA[0] += 32; gA[1] += 32; gB[0] += 32; gB[1] += 32;
    }
    __builtin_amdgcn_sched_barrier(0);
    compute(rb);
    rb = rb == 2 ? 0 : rb + 1;
    sb = sb == 2 ? 0 : sb + 1;
  }

  // ---- epilogue: bounce C tile through LDS for coalesced 16B stores --------
  __syncthreads();  // all waves done with K-loop LDS; smem is free
  // write: bias+relu, bf16, row-major [128][128] with 16B-block XOR swizzle:
  // byte = row*256 + col*2; byte ^= ((row>>2)&7)<<4  (conflict-free per instr)
#pragma unroll
  for (int nt = 0; nt < 4; nt++) {
    int cloc = wn * 64 + nt * 16 + lr;
    float bias = b1[(size_t)e * DH + hc0 + n0 + cloc];
#pragma unroll
    for (int mt = 0; mt < 4; mt++) {
#pragma unroll
      for (int r2 = 0; r2 < 4; r2++) {
        int row = wm * 64 + mt * 16 + quad * 4 + r2;
        float v = acc[mt][nt][r2] + bias;
        v = v > 0.f ? v : 0.f;
        int byte = (row * 256 + cloc * 2) ^ (((row >> 2) & 7) << 4);
        *(bf16*)((char*)smem + byte) = (bf16)v;
      }
    }
  }
  __syncthreads();
  // read back: 16 threads/row x 16B = 256B/row, 16 rows/pass, 8 passes
#pragma unroll
  for (int p = 0; p < 8; p++) {
    int r = p * 16 + (tid >> 4);
    int b = tid & 15;
    if (m0 + r < ne) {
      int byte = (r * 256 + b * 16) ^ (((r >> 2) & 7) << 4);
      bf16_8 v = *(const bf16_8*)((char*)smem + byte);
      *(bf16_8*)(h + (size_t)(off + m0 + r) * hchunk + n0 + b * 8) = v;
    }
  }
}

// ---------------- GEMM2: out[tok] += w_slot * (h @ W2t^T)  (fp32 atomics) ---
__global__ __launch_bounds__(256) void gemm2_kernel(
    const bf16* __restrict__ h, const bf16* __restrict__ W2t,
    const int* __restrict__ counts, const int* __restrict__ offsets,
    const int* __restrict__ mblk_off, const int* __restrict__ tok_list,
    const float* __restrict__ wt_list,
    float* __restrict__ out, int hchunk) {
  int nbx = gridDim.x;
  int orig = blockIdx.y * nbx + blockIdx.x;
  int nwg = nbx * gridDim.y;
  int wgid = (orig & 7) * (nwg >> 3) + (orig >> 3);
  int bxi = wgid % nbx;
  int mb = wgid / nbx;
  if (mb >= mblk_off[NE]) return;
  int e = 0;
  while (mb >= mblk_off[e + 1]) e++;
  int ne = counts[e];
  int m0 = (mb - mblk_off[e]) * 128;
  int off = offsets[e];
  int n0 = bxi * 128;

  __shared__ __align__(16) bf16 smem[6 * 128 * 32];
  bf16* ldsA = smem;
  bf16* ldsB = smem + 3 * 4096;

  int tid = threadIdx.x;
  int w = tid >> 6, lane = tid & 63;
  int scol = (((lane & 3) ^ (lane >> 3)) & 3) * 8;

  const bf16* gA[2]; const bf16* gB[2];
  bf16* lA[2]; bf16* lB[2];
#pragma unroll
  for (int j = 0; j < 2; j++) {
    int seg = w * 2 + j;
    int row = seg * 16 + (lane >> 2);
    gA[j] = h + (size_t)(off + m0 + row) * hchunk + scol;  // h padded +128 rows
    lA[j] = ldsA + seg * 512;
    gB[j] = W2t + ((size_t)e * DOUT + n0 + row) * hchunk + scol;
    lB[j] = ldsB + seg * 512;
  }

  f32_4 acc[4][4];
#pragma unroll
  for (int i = 0; i < 4; i++)
#pragma unroll
    for (int j = 0; j < 4; j++) acc[i][j] = (f32_4){0.f, 0.f, 0.f, 0.f};

  int wm = w & 1, wn = w >> 1;
  int lr = lane & 15, quad = lane >> 4;
  int rcol = ((quad ^ (lr >> 1)) & 3) * 8;

  auto compute = [&](int buf) {
    bf16_8 af[4], bfr[4];
#pragma unroll
    for (int mt = 0; mt < 4; mt++)
      af[mt] = *(const bf16_8*)(ldsA + buf * 4096 + (wm * 64 + mt * 16 + lr) * 32 + rcol);
#pragma unroll
    for (int nt = 0; nt < 4; nt++)
      bfr[nt] = *(const bf16_8*)(ldsB + buf * 4096 + (wn * 64 + nt * 16 + lr) * 32 + rcol);
#pragma unroll
    for (int mt = 0; mt < 4; mt++)
#pragma unroll
      for (int nt = 0; nt < 4; nt++)
        acc[mt][nt] = __builtin_amdgcn_mfma_f32_16x16x32_bf16(af[mt], bfr[nt], acc[mt][nt], 0, 0, 0);
  };

  const int nk = hchunk / 32;
  // prologue: stage tiles 0,1 into bufs 0,1
#pragma unroll
  for (int j = 0; j < 2; j++) { gl_lds16(gA[j], lA[j]); gl_lds16(gB[j], lB[j]); }
  gA[0] += 32; gA[1] += 32; gB[0] += 32; gB[1] += 32;
#pragma unroll
  for (int j = 0; j < 2; j++) { gl_lds16(gA[j], lA[j] + 4096); gl_lds16(gB[j], lB[j] + 4096); }
  gA[0] += 32; gA[1] += 32; gB[0] += 32; gB[1] += 32;

  int rb = 0, sb = 2;
  for (int kt = 0; kt < nk; kt++) {
    if (kt + 1 < nk) asm volatile("s_waitcnt vmcnt(4)" ::: "memory");
    else             asm volatile("s_waitcnt vmcnt(0)" ::: "memory");
    __builtin_amdgcn_s_barrier();
    __builtin_amdgcn_sched_barrier(0);
    if (kt + 2 < nk) {
#pragma unroll
      for (int j = 0; j < 2; j++) {
        gl_lds16(gA[j], lA[j] + sb * 4096);
        gl_lds16(gB[j], lB[j] + sb * 4096);
      }
      gA[0] += 32; gA[1] += 32; gB[0] += 32; gB[1] += 32;
    }
    __builtin_amdgcn_sched_barrier(0);
    compute(rb);
    rb = rb == 2 ? 0 : rb + 1;
    sb = sb == 2 ? 0 : sb + 1;
  }

  // ---- epilogue: weighted atomic accumulate directly into out --------------
#pragma unroll
  for (int mt = 0; mt < 4; mt++) {
#pragma unroll
    for (int r2 = 0; r2 < 4; r2++) {
      int row = wm * 64 + mt * 16 + quad * 4 + r2;
      if (m0 + row < ne) {
        int slot = off + m0 + row;
        int tok = tok_list[slot];
        float wgt = wt_list[slot];
        float* orow = out + (size_t)tok * DOUT + n0;
#pragma unroll
        for (int nt = 0; nt < 4; nt++) {
          int c = wn * 64 + nt * 16 + lr;
          atomicAdd(orow + c, wgt * acc[mt][nt][r2]);
        }
      }
    }
  }
}

// ---------------- host ------------------------------------------------------
extern "C" void kernel_launch(void* const* d_in, const int* in_sizes, int n_in,
                              void* d_out, int out_size, void* d_ws, size_t ws_size,
                              hipStream_t stream) {
  const float* x  = (const float*)d_in[0];
  const float* Wg = (const float*)d_in[1];
  const float* bg = (const float*)d_in[2];
  const float* W1 = (const float*)d_in[3];
  const float* b1 = (const float*)d_in[4];
  const float* W2 = (const float*)d_in[5];
  const float* b2 = (const float*)d_in[6];
  float* out = (float*)d_out;

  char* p = (char*)d_ws;
  int*   counts   = (int*)p;   p += 256;
  int*   offsets  = (int*)p;   p += 256;
  int*   mblk_off = (int*)p;   p += 256;
  int*   topi     = (int*)p;   p += 16384 * 4;
  float* topw     = (float*)p; p += 16384 * 4;
  int*   pos      = (int*)p;   p += 16384 * 4;
  int*   tok_list = (int*)p;   p += 16384 * 4;
  float* wt_list  = (float*)p; p += 16384 * 4;
  bf16*  xb       = (bf16*)p;  p += (size_t)NTOK * DIN * 2;

  size_t fixedBytes = (size_t)(p - (char*)d_ws);
  // per-hchunk bytes: h (16384+128 rows)*2 + W1t 8*1024*2 + W2t 8*1024*2 = 65792
  int hchunk = 4096;
  while (hchunk > 128 && fixedBytes + (size_t)hchunk * 65792 > ws_size) hchunk >>= 1;

  bf16* W1t  = (bf16*)p; p += (size_t)NE * hchunk * DIN * 2;
  bf16* W2t  = (bf16*)p; p += (size_t)NE * DOUT * hchunk * 2;
  bf16* hbuf = (bf16*)p; p += (size_t)(16384 + 128) * hchunk * 2;

  hipMemsetAsync(counts, 0, 32, stream);
  gate_kernel<<<NTOK / 4, 256, 0, stream>>>(x, Wg, bg, topi, topw, xb);
  hist_kernel<<<64, 256, 0, stream>>>(topi, counts, pos);
  scan_kernel<<<1, 64, 0, stream>>>(counts, offsets, mblk_off);
  pack_kernel<<<64, 256, 0, stream>>>(topi, pos, offsets, topw, tok_list, wt_list);
  prefill_kernel<<<NTOK, 256, 0, stream>>>(topi, topw, b2, out);

  int nchunks = DH / hchunk;
  for (int c = 0; c < nchunks; c++) {
    int hc0 = c * hchunk;
    // W1t[e][n][k] = W1[e][k][hc0+n]  (k rows: 1024, n cols: hchunk)
    tcvt_kernel<<<dim3(DIN / 32, hchunk / 32, NE), 256, 0, stream>>>(
        W1 + hc0, W1t, DH, (long long)DIN * DH, DIN, (long long)hchunk * DIN);
    // W2t[e][o][hk] = W2[e][hc0+hk][o] (hk rows: hchunk, o cols: 1024)
    tcvt_kernel<<<dim3(hchunk / 32, DOUT / 32, NE), 256, 0, stream>>>(
        W2 + (size_t)hc0 * DOUT, W2t, DOUT, (long long)DH * DOUT, hchunk, (long long)DOUT * hchunk);
    gemm1_kernel<<<dim3(hchunk / 128, MAXMB), 256, 0, stream>>>(
        xb, W1t, b1, counts, offsets, mblk_off, tok_list, hbuf, hchunk, hc0);
    gemm2_kernel<<<dim3(DOUT / 128, MAXMB), 256, 0, stream>>>(
        hbuf, W2t, counts, offsets, mblk_off, tok_list, wt_list, out, hchunk);
  }
}

// Round 6
// 767.509 us; speedup vs baseline: 1.0517x; 1.0116x over previous
//
#include <hip/hip_runtime.h>
#include <hip/hip_bf16.h>
#include <stdint.h>

#define NTOK 8192
#define NE 8
#define DIN 1024
#define DH 4096
#define DOUT 1024
#define MAXMB 135  // max total m-blocks: 16384/128 + 7 partial tails

typedef __bf16 bf16;
typedef __bf16 bf16_8 __attribute__((ext_vector_type(8)));
typedef __bf16 bf16_4 __attribute__((ext_vector_type(4)));
typedef float f32_4 __attribute__((ext_vector_type(4)));

__device__ __forceinline__ void gl_lds16(const void* g, void* l) {
  __builtin_amdgcn_global_load_lds(
      (const __attribute__((address_space(1))) unsigned int*)g,
      (__attribute__((address_space(3))) unsigned int*)l, 16, 0, 0);
}

// ---------------- gating: fp32 logits, top-2, softmax; fused x->bf16 --------
__global__ void gate_kernel(const float* __restrict__ x, const float* __restrict__ Wg,
                            const float* __restrict__ bg,
                            int* __restrict__ topi, float* __restrict__ topw,
                            bf16* __restrict__ xb) {
  int t = blockIdx.x * 4 + (threadIdx.x >> 6);
  int lane = threadIdx.x & 63;
  float acc[NE];
#pragma unroll
  for (int e = 0; e < NE; e++) acc[e] = 0.f;
  const float* xr = x + (size_t)t * DIN;
  bf16* xw = xb + (size_t)t * DIN;
#pragma unroll
  for (int i = 0; i < DIN / 64; i++) {
    float xv = xr[lane + 64 * i];
    xw[lane + 64 * i] = (bf16)xv;  // fused fp32->bf16 conversion
    const float4* wr = (const float4*)(Wg + (size_t)(lane + 64 * i) * NE);
    float4 w0 = wr[0], w1 = wr[1];
    acc[0] += xv * w0.x; acc[1] += xv * w0.y; acc[2] += xv * w0.z; acc[3] += xv * w0.w;
    acc[4] += xv * w1.x; acc[5] += xv * w1.y; acc[6] += xv * w1.z; acc[7] += xv * w1.w;
  }
#pragma unroll
  for (int off = 32; off > 0; off >>= 1)
#pragma unroll
    for (int e = 0; e < NE; e++) acc[e] += __shfl_xor(acc[e], off, 64);
  if (lane == 0) {
    float lg[NE];
#pragma unroll
    for (int e = 0; e < NE; e++) lg[e] = acc[e] + bg[e];
    int i0 = 0; float v0 = lg[0];
#pragma unroll
    for (int e = 1; e < NE; e++) if (lg[e] > v0) { v0 = lg[e]; i0 = e; }
    int i1 = -1; float v1 = -3.0e38f;
#pragma unroll
    for (int e = 0; e < NE; e++) if (e != i0 && lg[e] > v1) { v1 = lg[e]; i1 = e; }
    float ex = expf(v1 - v0);
    float w0 = 1.f / (1.f + ex);
    float w1 = ex / (1.f + ex);
    topi[2 * t] = i0; topi[2 * t + 1] = i1;
    topw[2 * t] = w0; topw[2 * t + 1] = w1;
  }
}

// ---------------- histogram: block-aggregated positions ---------------------
__global__ void hist_kernel(const int* __restrict__ topi, int* __restrict__ counts,
                            int* __restrict__ pos) {
  __shared__ int bins[NE];
  __shared__ int base[NE];
  int tid = threadIdx.x;
  if (tid < NE) bins[tid] = 0;
  __syncthreads();
  int i = blockIdx.x * 256 + tid;  // < 16384
  int e = topi[i];
  int local = atomicAdd(&bins[e], 1);
  __syncthreads();
  if (tid < NE) base[tid] = atomicAdd(&counts[tid], bins[tid]);
  __syncthreads();
  pos[i] = base[e] + local;
}

// offsets[e]: token-slot prefix; mblk_off[e]: m-block prefix (for grid compaction)
__global__ void scan_kernel(const int* counts, int* offsets, int* mblk_off) {
  if (threadIdx.x == 0) {
    int s = 0, b = 0;
    for (int e = 0; e < NE; e++) {
      offsets[e] = s; mblk_off[e] = b;
      s += counts[e]; b += (counts[e] + 127) >> 7;
    }
    mblk_off[NE] = b;
  }
}

__global__ void pack_kernel(const int* __restrict__ topi,
                            const int* __restrict__ pos, const int* __restrict__ offsets,
                            const float* __restrict__ topw,
                            int* __restrict__ tok_list, float* __restrict__ wt_list) {
  int i = blockIdx.x * 256 + threadIdx.x;  // < 16384
  int e = topi[i];
  int slot = offsets[e] + pos[i];
  tok_list[slot] = i >> 1;
  wt_list[slot] = topw[i];
}

// ---------------- prefill: out[t] = w0*b2[e0] + w1*b2[e1] -------------------
__global__ void prefill_kernel(const int* __restrict__ topi, const float* __restrict__ topw,
                               const float* __restrict__ b2, float* __restrict__ out) {
  int t = blockIdx.x;
  int c = threadIdx.x * 4;
  int e0 = topi[2 * t], e1 = topi[2 * t + 1];
  float w0 = topw[2 * t], w1 = topw[2 * t + 1];
  float4 p = *(const float4*)(b2 + (size_t)e0 * DOUT + c);
  float4 q = *(const float4*)(b2 + (size_t)e1 * DOUT + c);
  float4 o;
  o.x = w0 * p.x + w1 * q.x;
  o.y = w0 * p.y + w1 * q.y;
  o.z = w0 * p.z + w1 * q.z;
  o.w = w0 * p.w + w1 * q.w;
  *(float4*)(out + (size_t)t * DOUT + c) = o;
}

// ---------------- fused weight transpose + fp32->bf16, 64x64 tiles ----------
// blockIdx.y==0: W1t[e][n][k] = W1[e][k][hc0+n]   (k:DIN rows, n:hchunk cols)
// blockIdx.y==1: W2t[e][o][hk] = W2[e][hc0+hk][o] (hk:hchunk rows, o:DOUT cols)
// Vectorized both sides: float4 coalesced reads, bf16_8 coalesced writes.
// LDS [64][66] (pad=2): write-phase and read-phase both <=2-way banks (free).
__global__ __launch_bounds__(256) void wt_kernel(
    const float* __restrict__ W1, const float* __restrict__ W2,
    bf16* __restrict__ W1t, bf16* __restrict__ W2t, int hchunk, int hc0) {
  __shared__ bf16 tile[64][66];
  int idx = blockIdx.x;
  int e = blockIdx.z;
  const float* src; bf16* dst; int sld, dld;
  if (blockIdx.y == 0) {
    int nkt = DIN / 64;  // 16
    int tk = idx % nkt, tn = idx / nkt;
    src = W1 + (size_t)e * DIN * DH + (size_t)(tk * 64) * DH + hc0 + tn * 64;
    dst = W1t + (size_t)e * hchunk * DIN + (size_t)(tn * 64) * DIN + tk * 64;
    sld = DH; dld = DIN;
  } else {
    int nkt = hchunk / 64;
    int tk = idx % nkt, tn = idx / nkt;
    src = W2 + (size_t)e * DH * DOUT + (size_t)(hc0 + tk * 64) * DOUT + tn * 64;
    dst = W2t + (size_t)e * DOUT * hchunk + (size_t)(tn * 64) * hchunk + tk * 64;
    sld = DOUT; dld = hchunk;
  }
  int tid = threadIdx.x;
  int r = tid >> 4, c = (tid & 15) * 4;  // 16 rows/pass, 4 passes
#pragma unroll
  for (int p = 0; p < 4; p++) {
    float4 v = *(const float4*)(src + (size_t)(p * 16 + r) * sld + c);
    bf16_4 b;
    b[0] = (bf16)v.x; b[1] = (bf16)v.y; b[2] = (bf16)v.z; b[3] = (bf16)v.w;
    *(bf16_4*)(&tile[p * 16 + r][c]) = b;
  }
  __syncthreads();
  int n = tid >> 3, k8 = (tid & 7) * 8;  // 32 out-rows/pass, 2 passes
#pragma unroll
  for (int p = 0; p < 2; p++) {
    int nn = p * 32 + n;
    bf16_8 o;
#pragma unroll
    for (int j = 0; j < 8; j++) o[j] = tile[k8 + j][nn];
    *(bf16_8*)(dst + (size_t)nn * dld + k8) = o;
  }
}

// Bank-conflict swizzle: within each 64B LDS row (4 x 16B cols), col' = col ^ ((row&15)>>1) & 3.
// Gather side: lane l in a segment stages global col ((l&3)^(l>>3))&3 of row l>>2,
// keeping lane->LDS contiguity for global_load_lds.

// Pipeline (verified r2, 769us): 3 LDS buffers; per iter: counted vmcnt(4) wait,
// barrier, ISSUE stage of tile kt+2, then ds_read+MFMA of tile kt.

// ---------------- GEMM1: h = relu(gather(xb) @ W1t^T + b1) ------------------
__global__ __launch_bounds__(256) void gemm1_kernel(
    const bf16* __restrict__ xb, const bf16* __restrict__ W1t,
    const float* __restrict__ b1, const int* __restrict__ counts,
    const int* __restrict__ offsets, const int* __restrict__ mblk_off,
    const int* __restrict__ tok_list,
    bf16* __restrict__ h, int hchunk, int hc0) {
  int nbx = gridDim.x;
  int orig = blockIdx.y * nbx + blockIdx.x;
  int nwg = nbx * gridDim.y;
  int wgid = (orig & 7) * (nwg >> 3) + (orig >> 3);
  int bxi = wgid % nbx;
  int mb = wgid / nbx;
  if (mb >= mblk_off[NE]) return;
  int e = 0;
  while (mb >= mblk_off[e + 1]) e++;
  int ne = counts[e];
  int m0 = (mb - mblk_off[e]) * 128;
  int off = offsets[e];
  int n0 = bxi * 128;

  __shared__ __align__(16) bf16 smem[6 * 128 * 32];  // 48 KB: 3 bufs x (A+B)
  bf16* ldsA = smem;
  bf16* ldsB = smem + 3 * 4096;

  int tid = threadIdx.x;
  int w = tid >> 6, lane = tid & 63;
  int scol = (((lane & 3) ^ (lane >> 3)) & 3) * 8;  // swizzled 16B col for staging

  const bf16* gA[2]; const bf16* gB[2];
  bf16* lA[2]; bf16* lB[2];
#pragma unroll
  for (int j = 0; j < 2; j++) {
    int seg = w * 2 + j;
    int row = seg * 16 + (lane >> 2);
    int slot = off + m0 + row;
    int smax = off + ne - 1;
    if (slot > smax) slot = smax;           // clamp tail rows to a valid token
    int tok = tok_list[slot];
    gA[j] = xb + (size_t)tok * DIN + scol;
    lA[j] = ldsA + seg * 512;               // wave-uniform base; HW adds lane*16B
    gB[j] = W1t + ((size_t)e * hchunk + n0 + row) * DIN + scol;
    lB[j] = ldsB + seg * 512;
  }

  f32_4 acc[4][4];
#pragma unroll
  for (int i = 0; i < 4; i++)
#pragma unroll
    for (int j = 0; j < 4; j++) acc[i][j] = (f32_4){0.f, 0.f, 0.f, 0.f};

  int wm = w & 1, wn = w >> 1;
  int lr = lane & 15, quad = lane >> 4;
  int rcol = ((quad ^ (lr >> 1)) & 3) * 8;

  auto compute = [&](int buf) {
    bf16_8 af[4], bfr[4];
#pragma unroll
    for (int mt = 0; mt < 4; mt++)
      af[mt] = *(const bf16_8*)(ldsA + buf * 4096 + (wm * 64 + mt * 16 + lr) * 32 + rcol);
#pragma unroll
    for (int nt = 0; nt < 4; nt++)
      bfr[nt] = *(const bf16_8*)(ldsB + buf * 4096 + (wn * 64 + nt * 16 + lr) * 32 + rcol);
#pragma unroll
    for (int mt = 0; mt < 4; mt++)
#pragma unroll
      for (int nt = 0; nt < 4; nt++)
        acc[mt][nt] = __builtin_amdgcn_mfma_f32_16x16x32_bf16(af[mt], bfr[nt], acc[mt][nt], 0, 0, 0);
  };

  const int nk = DIN / 32;
  // prologue: stage tiles 0,1 into bufs 0,1
#pragma unroll
  for (int j = 0; j < 2; j++) { gl_lds16(gA[j], lA[j]); gl_lds16(gB[j], lB[j]); }
  gA[0] += 32; gA[1] += 32; gB[0] += 32; gB[1] += 32;
#pragma unroll
  for (int j = 0; j < 2; j++) { gl_lds16(gA[j], lA[j] + 4096); gl_lds16(gB[j], lB[j] + 4096); }
  gA[0] += 32; gA[1] += 32; gB[0] += 32; gB[1] += 32;

  int rb = 0, sb = 2;
  for (int kt = 0; kt < nk; kt++) {
    if (kt + 1 < nk) asm volatile("s_waitcnt vmcnt(4)" ::: "memory");
    else             asm volatile("s_waitcnt vmcnt(0)" ::: "memory");
    __builtin_amdgcn_s_barrier();
    __builtin_amdgcn_sched_barrier(0);
    if (kt + 2 < nk) {
#pragma unroll
      for (int j = 0; j < 2; j++) {
        gl_lds16(gA[j], lA[j] + sb * 4096);
        gl_lds16(gB[j], lB[j] + sb * 4096);
      }
      gA[0] += 32; gA[1] += 32; gB[0] += 32; gB[1] += 32;
    }
    __builtin_amdgcn_sched_barrier(0);
    compute(rb);
    rb = rb == 2 ? 0 : rb + 1;
    sb = sb == 2 ? 0 : sb + 1;
  }

  // ---- epilogue: bounce C tile through LDS for coalesced 16B stores --------
  __syncthreads();  // all waves done with K-loop LDS; smem is free
  // write: bias+relu, bf16, row-major [128][128] with 16B-block XOR swizzle:
  // byte = row*256 + col*2; byte ^= ((row>>2)&7)<<4  (conflict-free per instr)
#pragma unroll
  for (int nt = 0; nt < 4; nt++) {
    int cloc = wn * 64 + nt * 16 + lr;
    float bias = b1[(size_t)e * DH + hc0 + n0 + cloc];
#pragma unroll
    for (int mt = 0; mt < 4; mt++) {
#pragma unroll
      for (int r2 = 0; r2 < 4; r2++) {
        int row = wm * 64 + mt * 16 + quad * 4 + r2;
        float v = acc[mt][nt][r2] + bias;
        v = v > 0.f ? v : 0.f;
        int byte = (row * 256 + cloc * 2) ^ (((row >> 2) & 7) << 4);
        *(bf16*)((char*)smem + byte) = (bf16)v;
      }
    }
  }
  __syncthreads();
  // read back: 16 threads/row x 16B = 256B/row, 16 rows/pass, 8 passes
#pragma unroll
  for (int p = 0; p < 8; p++) {
    int r = p * 16 + (tid >> 4);
    int b = tid & 15;
    if (m0 + r < ne) {
      int byte = (r * 256 + b * 16) ^ (((r >> 2) & 7) << 4);
      bf16_8 v = *(const bf16_8*)((char*)smem + byte);
      *(bf16_8*)(h + (size_t)(off + m0 + r) * hchunk + n0 + b * 8) = v;
    }
  }
}

// ---------------- GEMM2: out[tok] += w_slot * (h @ W2t^T)  (fp32 atomics) ---
__global__ __launch_bounds__(256) void gemm2_kernel(
    const bf16* __restrict__ h, const bf16* __restrict__ W2t,
    const int* __restrict__ counts, const int* __restrict__ offsets,
    const int* __restrict__ mblk_off, const int* __restrict__ tok_list,
    const float* __restrict__ wt_list,
    float* __restrict__ out, int hchunk) {
  int nbx = gridDim.x;
  int orig = blockIdx.y * nbx + blockIdx.x;
  int nwg = nbx * gridDim.y;
  int wgid = (orig & 7) * (nwg >> 3) + (orig >> 3);
  int bxi = wgid % nbx;
  int mb = wgid / nbx;
  if (mb >= mblk_off[NE]) return;
  int e = 0;
  while (mb >= mblk_off[e + 1]) e++;
  int ne = counts[e];
  int m0 = (mb - mblk_off[e]) * 128;
  int off = offsets[e];
  int n0 = bxi * 128;

  __shared__ __align__(16) bf16 smem[6 * 128 * 32];
  bf16* ldsA = smem;
  bf16* ldsB = smem + 3 * 4096;

  int tid = threadIdx.x;
  int w = tid >> 6, lane = tid & 63;
  int scol = (((lane & 3) ^ (lane >> 3)) & 3) * 8;

  const bf16* gA[2]; const bf16* gB[2];
  bf16* lA[2]; bf16* lB[2];
#pragma unroll
  for (int j = 0; j < 2; j++) {
    int seg = w * 2 + j;
    int row = seg * 16 + (lane >> 2);
    gA[j] = h + (size_t)(off + m0 + row) * hchunk + scol;  // h padded +128 rows
    lA[j] = ldsA + seg * 512;
    gB[j] = W2t + ((size_t)e * DOUT + n0 + row) * hchunk + scol;
    lB[j] = ldsB + seg * 512;
  }

  f32_4 acc[4][4];
#pragma unroll
  for (int i = 0; i < 4; i++)
#pragma unroll
    for (int j = 0; j < 4; j++) acc[i][j] = (f32_4){0.f, 0.f, 0.f, 0.f};

  int wm = w & 1, wn = w >> 1;
  int lr = lane & 15, quad = lane >> 4;
  int rcol = ((quad ^ (lr >> 1)) & 3) * 8;

  auto compute = [&](int buf) {
    bf16_8 af[4], bfr[4];
#pragma unroll
    for (int mt = 0; mt < 4; mt++)
      af[mt] = *(const bf16_8*)(ldsA + buf * 4096 + (wm * 64 + mt * 16 + lr) * 32 + rcol);
#pragma unroll
    for (int nt = 0; nt < 4; nt++)
      bfr[nt] = *(const bf16_8*)(ldsB + buf * 4096 + (wn * 64 + nt * 16 + lr) * 32 + rcol);
#pragma unroll
    for (int mt = 0; mt < 4; mt++)
#pragma unroll
      for (int nt = 0; nt < 4; nt++)
        acc[mt][nt] = __builtin_amdgcn_mfma_f32_16x16x32_bf16(af[mt], bfr[nt], acc[mt][nt], 0, 0, 0);
  };

  const int nk = hchunk / 32;
  // prologue: stage tiles 0,1 into bufs 0,1
#pragma unroll
  for (int j = 0; j < 2; j++) { gl_lds16(gA[j], lA[j]); gl_lds16(gB[j], lB[j]); }
  gA[0] += 32; gA[1] += 32; gB[0] += 32; gB[1] += 32;
#pragma unroll
  for (int j = 0; j < 2; j++) { gl_lds16(gA[j], lA[j] + 4096); gl_lds16(gB[j], lB[j] + 4096); }
  gA[0] += 32; gA[1] += 32; gB[0] += 32; gB[1] += 32;

  int rb = 0, sb = 2;
  for (int kt = 0; kt < nk; kt++) {
    if (kt + 1 < nk) asm volatile("s_waitcnt vmcnt(4)" ::: "memory");
    else             asm volatile("s_waitcnt vmcnt(0)" ::: "memory");
    __builtin_amdgcn_s_barrier();
    __builtin_amdgcn_sched_barrier(0);
    if (kt + 2 < nk) {
#pragma unroll
      for (int j = 0; j < 2; j++) {
        gl_lds16(gA[j], lA[j] + sb * 4096);
        gl_lds16(gB[j], lB[j] + sb * 4096);
      }
      gA[0] += 32; gA[1] += 32; gB[0] += 32; gB[1] += 32;
    }
    __builtin_amdgcn_sched_barrier(0);
    compute(rb);
    rb = rb == 2 ? 0 : rb + 1;
    sb = sb == 2 ? 0 : sb + 1;
  }

  // ---- epilogue: weighted atomic accumulate directly into out --------------
#pragma unroll
  for (int mt = 0; mt < 4; mt++) {
#pragma unroll
    for (int r2 = 0; r2 < 4; r2++) {
      int row = wm * 64 + mt * 16 + quad * 4 + r2;
      if (m0 + row < ne) {
        int slot = off + m0 + row;
        int tok = tok_list[slot];
        float wgt = wt_list[slot];
        float* orow = out + (size_t)tok * DOUT + n0;
#pragma unroll
        for (int nt = 0; nt < 4; nt++) {
          int c = wn * 64 + nt * 16 + lr;
          atomicAdd(orow + c, wgt * acc[mt][nt][r2]);
        }
      }
    }
  }
}

// ---------------- host ------------------------------------------------------
extern "C" void kernel_launch(void* const* d_in, const int* in_sizes, int n_in,
                              void* d_out, int out_size, void* d_ws, size_t ws_size,
                              hipStream_t stream) {
  const float* x  = (const float*)d_in[0];
  const float* Wg = (const float*)d_in[1];
  const float* bg = (const float*)d_in[2];
  const float* W1 = (const float*)d_in[3];
  const float* b1 = (const float*)d_in[4];
  const float* W2 = (const float*)d_in[5];
  const float* b2 = (const float*)d_in[6];
  float* out = (float*)d_out;

  char* p = (char*)d_ws;
  int*   counts   = (int*)p;   p += 256;
  int*   offsets  = (int*)p;   p += 256;
  int*   mblk_off = (int*)p;   p += 256;
  int*   topi     = (int*)p;   p += 16384 * 4;
  float* topw     = (float*)p; p += 16384 * 4;
  int*   pos      = (int*)p;   p += 16384 * 4;
  int*   tok_list = (int*)p;   p += 16384 * 4;
  float* wt_list  = (float*)p; p += 16384 * 4;
  bf16*  xb       = (bf16*)p;  p += (size_t)NTOK * DIN * 2;

  size_t fixedBytes = (size_t)(p - (char*)d_ws);
  // per-hchunk bytes: h (16384+128 rows)*2 + W1t 8*1024*2 + W2t 8*1024*2 = 65792
  int hchunk = 4096;
  while (hchunk > 128 && fixedBytes + (size_t)hchunk * 65792 > ws_size) hchunk >>= 1;

  bf16* W1t  = (bf16*)p; p += (size_t)NE * hchunk * DIN * 2;
  bf16* W2t  = (bf16*)p; p += (size_t)NE * DOUT * hchunk * 2;
  bf16* hbuf = (bf16*)p; p += (size_t)(16384 + 128) * hchunk * 2;

  hipMemsetAsync(counts, 0, 32, stream);
  gate_kernel<<<NTOK / 4, 256, 0, stream>>>(x, Wg, bg, topi, topw, xb);
  hist_kernel<<<64, 256, 0, stream>>>(topi, counts, pos);
  scan_kernel<<<1, 64, 0, stream>>>(counts, offsets, mblk_off);
  pack_kernel<<<64, 256, 0, stream>>>(topi, pos, offsets, topw, tok_list, wt_list);
  prefill_kernel<<<NTOK, 256, 0, stream>>>(topi, topw, b2, out);

  int nchunks = DH / hchunk;
  for (int c = 0; c < nchunks; c++) {
    int hc0 = c * hchunk;
    // fused W1t/W2t transpose: ntiles identical for both (DIN==DOUT)
    int ntiles = (DIN / 64) * (hchunk / 64);
    wt_kernel<<<dim3(ntiles, 2, NE), 256, 0, stream>>>(W1, W2, W1t, W2t, hchunk, hc0);
    gemm1_kernel<<<dim3(hchunk / 128, MAXMB), 256, 0, stream>>>(
        xb, W1t, b1, counts, offsets, mblk_off, tok_list, hbuf, hchunk, hc0);
    gemm2_kernel<<<dim3(DOUT / 128, MAXMB), 256, 0, stream>>>(
        hbuf, W2t, counts, offsets, mblk_off, tok_list, wt_list, out, hchunk);
  }
}